// Round 18
// baseline (273.133 us; speedup 1.0000x reference)
//
#include <hip/hip_runtime.h>
#include <hip/hip_bf16.h>

#define C 128
#define NBMAX 256      // max coarse buckets (key >> 10)
#define EPB 16384      // entries per k_part2 block (8192 edges)
#define BCAP 18432     // fixed bucket capacity in tmp (mean 16.4K + 16 sigma)
#define CCAP 25600     // fixed bucket capacity in csr (BCAP + 1024*7 pad)

typedef __attribute__((ext_vector_type(8))) short bf16x8;
typedef __attribute__((ext_vector_type(4))) float f32x4;
typedef __attribute__((ext_vector_type(2))) float f32x2;

__device__ __forceinline__ unsigned short f2bf(float f) {
    unsigned u = __builtin_bit_cast(unsigned, f);
    u += 0x7fff + ((u >> 16) & 1);          // RNE
    return (unsigned short)(u >> 16);
}
__device__ __forceinline__ float bf1(unsigned short v) {
    return __builtin_bit_cast(float, (unsigned)v << 16);
}

// ---- fp8 e4m3 helpers (HW cvt on gfx950, software fallback) ----------------
__device__ __forceinline__ unsigned char f2fp8(float v) {
#if __has_builtin(__builtin_amdgcn_cvt_pk_fp8_f32)
    return (unsigned char)(__builtin_amdgcn_cvt_pk_fp8_f32(v, v, 0, false) & 0xff);
#else
    unsigned u = __builtin_bit_cast(unsigned, v);
    if (v < 0.015625f) return 0;
    u += 0x7FFFF + ((u >> 20) & 1);
    int e = (int)(u >> 23) - 120;
    int m = (u >> 20) & 7;
    if (e <= 0) return 0;
    if (e > 15) return 0x7E;
    return (unsigned char)((e << 3) | m);
#endif
}

__device__ __forceinline__ unsigned f2fp8x2(float a, float b) {
#if __has_builtin(__builtin_amdgcn_cvt_pk_fp8_f32)
    return (unsigned)(__builtin_amdgcn_cvt_pk_fp8_f32(a, b, 0, false) & 0xffff);
#else
    return (unsigned)f2fp8(a) | ((unsigned)f2fp8(b) << 8);
#endif
}

template <bool HI>
__device__ __forceinline__ f32x2 fp8x2_dec(unsigned q) {
#if __has_builtin(__builtin_amdgcn_cvt_pk_f32_fp8)
    return __builtin_amdgcn_cvt_pk_f32_fp8((int)q, HI);
#else
    unsigned short v = HI ? (unsigned short)(q >> 16) : (unsigned short)(q & 0xffff);
    auto dec1 = [](unsigned b) -> float {
        unsigned r = ((b & 0x80u) << 8) | (((b & 0x7fu) << 4) + 0x3C00u);
        if ((b & 0x78u) == 0) r = 0;
        return __builtin_bit_cast(float, r << 16);
    };
    f32x2 r; r[0] = dec1(v & 0xff); r[1] = dec1(v >> 8);
    return r;
#endif
}

// ---------------- k_emb: x_emb = x @ W1^T (bf16), mu = relu(..) (fp8) -------
// Extra duties: block 0 zeroes bcnt/out/mu-zero-row and writes csr sentinel;
// blocks 0..7 convert W2|W3 -> bf16 swizzled global (wsw) for k_mm3.
__global__ __launch_bounds__(512) void k_emb(
    const float* __restrict__ x, const float* __restrict__ W1,
    const float* __restrict__ W2, const float* __restrict__ W3,
    unsigned short* __restrict__ x_emb, unsigned char* __restrict__ mu,
    unsigned short* __restrict__ wsw, int* __restrict__ bcnt,
    float* __restrict__ out, int* __restrict__ csr, int nN)
{
    __shared__ unsigned short Wl[C * C];   // bf16, XOR-swizzled 16B chunks
    const int t = threadIdx.x;

    if (blockIdx.x == 0) {
        for (int i = t; i < NBMAX * 16; i += 512) bcnt[i] = 0;
        if (t < C) out[t] = 0.f;
        if (t < C / 4) ((unsigned*)(mu + (size_t)nN * C))[t] = 0u;
        if (t < 8) csr[t] = nN;            // global sentinel chunk -> zero row
    }
    if (blockIdx.x < 8) {   // W2|W3 -> wsw (4096 chunks of 8 elems)
        int i = blockIdx.x * 512 + t;
        int wsel = i >> 11, r = i & 2047;
        int j = r >> 4, c = r & 15;
        const float* srcp = (wsel ? W3 : W2) + j * C + c * 8;
        float4 f0 = *(const float4*)srcp;
        float4 f1 = *(const float4*)(srcp + 4);
        alignas(16) unsigned short tmp[8] = {
            f2bf(f0.x), f2bf(f0.y), f2bf(f0.z), f2bf(f0.w),
            f2bf(f1.x), f2bf(f1.y), f2bf(f1.z), f2bf(f1.w)};
        int cs = c ^ (j & 7);
        *(uint4*)&wsw[wsel * C * C + j * C + cs * 8] = *(const uint4*)tmp;
    }

    for (int i = t; i < C * C / 8; i += 512) {
        int j = i >> 4, c = i & 15;
        const float* srcp = W1 + j * C + c * 8;
        float4 f0 = *(const float4*)srcp;
        float4 f1 = *(const float4*)(srcp + 4);
        alignas(16) unsigned short tmp[8] = {
            f2bf(f0.x), f2bf(f0.y), f2bf(f0.z), f2bf(f0.w),
            f2bf(f1.x), f2bf(f1.y), f2bf(f1.z), f2bf(f1.w)};
        int cs = c ^ (j & 7);
        *(uint4*)&Wl[j * C + cs * 8] = *(const uint4*)tmp;
    }
    __syncthreads();

    const int lane = t & 63, w = t >> 6;
    const int r0 = blockIdx.x * 128 + w * 16;
    if (r0 >= nN) return;
    const int lj = lane & 15, lk = lane >> 4;
    const int arow = r0 + lj;

    bf16x8 a[4];
    #pragma unroll
    for (int ks = 0; ks < 4; ++ks) {
        const float* ap = x + (size_t)arow * C + ks * 32 + lk * 8;
        float4 f0 = *(const float4*)ap;
        float4 f1 = *(const float4*)(ap + 4);
        alignas(16) unsigned short tmp[8] = {
            f2bf(f0.x), f2bf(f0.y), f2bf(f0.z), f2bf(f0.w),
            f2bf(f1.x), f2bf(f1.y), f2bf(f1.z), f2bf(f1.w)};
        a[ks] = *(const bf16x8*)tmp;
    }

    #pragma unroll
    for (int ct = 0; ct < 8; ++ct) {
        int j = ct * 16 + lj;
        f32x4 acc = {0.f, 0.f, 0.f, 0.f};
        #pragma unroll
        for (int ks = 0; ks < 4; ++ks) {
            int slot = (ks * 4 + lk) ^ (j & 7);
            bf16x8 b = *(const bf16x8*)&Wl[j * C + slot * 8];
            acc = __builtin_amdgcn_mfma_f32_16x16x32_bf16(a[ks], b, acc, 0, 0, 0);
        }
        #pragma unroll
        for (int r = 0; r < 4; ++r) {
            int row = r0 + lk * 4 + r;
            float v = acc[r];
            x_emb[(size_t)row * C + j] = f2bf(v);
            mu[(size_t)row * C + j] = f2fp8(fminf(fmaxf(v, 0.f), 448.f));
        }
    }
}

// ---- k_mm3: mu' = relu(x_emb + s_in @ W2^T + s_out @ W3^T) -----------------
// s_in/s_out fp8 (nontemporal reads); W from pre-converted wsw.
// FINAL=0: write mu' fp8. FINAL=1: column-reduce into out[128].
template<int FINAL>
__global__ __launch_bounds__(512) void k_mm3(
    const unsigned char* __restrict__ s_in, const unsigned char* __restrict__ s_out,
    const unsigned short* __restrict__ wsw,
    const unsigned short* __restrict__ x_emb,
    unsigned char* __restrict__ mu_out, float* __restrict__ out, int nN)
{
    __shared__ unsigned short Wl[2 * C * C];   // W2 then W3, swizzled
    __shared__ float redf[8 * C];              // FINAL column partials
    const int t = threadIdx.x;
    for (int i = t; i < 2 * C * C / 8; i += 512)
        *(uint4*)&Wl[i * 8] = *(const uint4*)&wsw[i * 8];
    if (FINAL) {
        for (int i = t; i < 8 * C; i += 512) redf[i] = 0.f;
    }
    __syncthreads();

    const int lane = t & 63, w = t >> 6;
    const int r0 = blockIdx.x * 128 + w * 16;
    const int lj = lane & 15, lk = lane >> 4;
    const bool active = (r0 < nN);

    if (active) {
        const int arow = r0 + lj;
        bf16x8 a2[4], a3[4];
        #pragma unroll
        for (int ks = 0; ks < 4; ++ks) {
            unsigned long long qiL = __builtin_nontemporal_load(
                (const unsigned long long*)&s_in [(size_t)arow * C + ks * 32 + lk * 8]);
            unsigned long long qoL = __builtin_nontemporal_load(
                (const unsigned long long*)&s_out[(size_t)arow * C + ks * 32 + lk * 8]);
            unsigned qix = (unsigned)qiL, qiy = (unsigned)(qiL >> 32);
            unsigned qox = (unsigned)qoL, qoy = (unsigned)(qoL >> 32);
            f32x2 e0 = fp8x2_dec<false>(qix), e1 = fp8x2_dec<true>(qix);
            f32x2 e2 = fp8x2_dec<false>(qiy), e3 = fp8x2_dec<true>(qiy);
            a2[ks][0] = (short)f2bf(e0[0]); a2[ks][1] = (short)f2bf(e0[1]);
            a2[ks][2] = (short)f2bf(e1[0]); a2[ks][3] = (short)f2bf(e1[1]);
            a2[ks][4] = (short)f2bf(e2[0]); a2[ks][5] = (short)f2bf(e2[1]);
            a2[ks][6] = (short)f2bf(e3[0]); a2[ks][7] = (short)f2bf(e3[1]);
            f32x2 g0 = fp8x2_dec<false>(qox), g1 = fp8x2_dec<true>(qox);
            f32x2 g2 = fp8x2_dec<false>(qoy), g3 = fp8x2_dec<true>(qoy);
            a3[ks][0] = (short)f2bf(g0[0]); a3[ks][1] = (short)f2bf(g0[1]);
            a3[ks][2] = (short)f2bf(g1[0]); a3[ks][3] = (short)f2bf(g1[1]);
            a3[ks][4] = (short)f2bf(g2[0]); a3[ks][5] = (short)f2bf(g2[1]);
            a3[ks][6] = (short)f2bf(g3[0]); a3[ks][7] = (short)f2bf(g3[1]);
        }

        #pragma unroll
        for (int ct = 0; ct < 8; ++ct) {
            int j = ct * 16 + lj;
            f32x4 acc = {0.f, 0.f, 0.f, 0.f};
            #pragma unroll
            for (int ks = 0; ks < 4; ++ks) {
                int slot = (ks * 4 + lk) ^ (j & 7);
                bf16x8 b2 = *(const bf16x8*)&Wl[j * C + slot * 8];
                bf16x8 b3 = *(const bf16x8*)&Wl[C * C + j * C + slot * 8];
                acc = __builtin_amdgcn_mfma_f32_16x16x32_bf16(a2[ks], b2, acc, 0, 0, 0);
                acc = __builtin_amdgcn_mfma_f32_16x16x32_bf16(a3[ks], b3, acc, 0, 0, 0);
            }
            float vsum = 0.f;
            #pragma unroll
            for (int r = 0; r < 4; ++r) {
                int row = r0 + lk * 4 + r;
                float v = acc[r] + bf1(__builtin_nontemporal_load(
                    &x_emb[(size_t)row * C + j]));
                v = fmaxf(v, 0.f);
                if (FINAL) vsum += v;
                else mu_out[(size_t)row * C + j] = f2fp8(fminf(v, 448.f));
            }
            if (FINAL) {
                float s = vsum;
                s += __shfl_xor(s, 16);
                s += __shfl_xor(s, 32);
                if (lk == 0) redf[w * C + j] = s;
            }
        }
    }
    if (FINAL) {
        __syncthreads();
        if (t < C) {
            float acc = 0.f;
            #pragma unroll
            for (int ww = 0; ww < 8; ++ww) acc += redf[ww * C + t];
            atomicAdd(&out[t], acc);
        }
    }
}

// ---------------- CSR build pass 1: block-local counting sort ---------------
__global__ __launch_bounds__(512) void k_part2(
    const int* __restrict__ src, const int* __restrict__ dst,
    int* __restrict__ bcnt, unsigned* __restrict__ tmp, int nE, int nN, int n2)
{
    __shared__ unsigned sbuf[EPB];
    __shared__ unsigned char bid[EPB];
    __shared__ int hist[NBMAX], lstart[NBMAX], cur[NBMAX], gbase[NBMAX];

    const int t = threadIdx.x;
    const int e0 = blockIdx.x * (EPB / 2);
    const int e1 = min(e0 + EPB / 2, nE);

    for (int b = t; b < NBMAX; b += 512) { hist[b] = 0; cur[b] = 0; }
    __syncthreads();

    for (int e = e0 + t; e < e1; e += 512) {
        int s = src[e], d = dst[e];
        atomicAdd(&hist[(2 * d) >> 10], 1);
        atomicAdd(&hist[(2 * s + 1) >> 10], 1);
    }
    __syncthreads();

    for (int o = 1; o < NBMAX; o <<= 1) {
        int v = 0;
        if (t < NBMAX && t >= o) v = hist[t - o];
        __syncthreads();
        if (t < NBMAX) hist[t] += v;
        __syncthreads();
    }
    if (t < NBMAX) {
        int ls = (t == 0) ? 0 : hist[t - 1];
        lstart[t] = ls;
        int c = hist[t] - ls;
        if (c > 0)
            gbase[t] = t * BCAP + atomicAdd(&bcnt[t * 16], c);
    }
    __syncthreads();

    for (int e = e0 + t; e < e1; e += 512) {
        int s = src[e], d = dst[e];
        {
            int key = 2 * d, b = key >> 10, krel = key & 1023;
            int pos = lstart[b] + atomicAdd(&cur[b], 1);
            sbuf[pos] = ((unsigned)krel << 17) | (unsigned)s;
            bid[pos] = (unsigned char)b;
        }
        {
            int key = 2 * s + 1, b = key >> 10, krel = key & 1023;
            int pos = lstart[b] + atomicAdd(&cur[b], 1);
            sbuf[pos] = ((unsigned)krel << 17) | (unsigned)d;
            bid[pos] = (unsigned char)b;
        }
    }
    __syncthreads();

    const int nent = 2 * (e1 - e0);
    for (int j = t; j < nent; j += 512) {
        int b = bid[j];
        tmp[gbase[b] + (j - lstart[b])] = sbuf[j];
    }
}

// ---------------- k_place: merged histogram + scan + off/deg + scatter ------
__global__ __launch_bounds__(512) void k_place(
    const unsigned* __restrict__ tmp, const int* __restrict__ bcnt,
    int* __restrict__ off, int* __restrict__ deg, int* __restrict__ csr,
    int n2, int zrow)
{
    __shared__ int cnt[1024], excl[1024], part[512];
    const int t = threadIdx.x;
    const int b = blockIdx.x;
    const int key0 = b << 10;
    const int s0 = b * BCAP;
    const int s1 = s0 + bcnt[b * 16];
    const int pb0 = 8 + b * CCAP;

    for (int i = t; i < 1024; i += 512) cnt[i] = 0;
    __syncthreads();
    for (int i = s0 + t; i < s1; i += 512)
        atomicAdd(&cnt[tmp[i] >> 17], 1);
    __syncthreads();

    const int base = t * 2;
    int c0 = cnt[base], c1 = cnt[base + 1];
    int p0 = (c0 + 7) & ~7, p1v = (c1 + 7) & ~7;
    int s = p0 + p1v;
    part[t] = s;
    for (int o = 1; o < 512; o <<= 1) {
        __syncthreads();
        int v = (t >= o) ? part[t - o] : 0;
        __syncthreads();
        part[t] += v;
    }
    __syncthreads();
    int pe = part[t] - s;
    excl[base]     = pe;
    excl[base + 1] = pe + p0;
    __syncthreads();

    for (int i = t; i < 1024; i += 512) {
        int key = key0 + i;
        if (key < n2) {
            int o = pb0 + excl[i];
            off[key] = o;
            int d = cnt[i];
            deg[key] = d;
            int pd = (d + 7) & ~7;
            for (int p = d; p < pd; ++p) csr[o + p] = zrow;
        }
    }
    __syncthreads();
    for (int i = t; i < 1024; i += 512) cnt[i] = 0;   // reuse as cursors
    __syncthreads();

    for (int i = s0 + t; i < s1; i += 512) {
        unsigned p = tmp[i];
        int krel = p >> 17;
        int val  = p & 0x1FFFF;
        int pos  = pb0 + excl[krel] + atomicAdd(&cnt[krel], 1);
        csr[pos] = val;
    }
}

// ---- k_aggM: s_in[g] = sum(mu[in]), s_out[g] = sum(mu[out])  (fp8 in/out) --
// 16 lanes per node (8 ch/lane, uint2 loads), 4 nodes per wave, MLP=16.
// csr loads + s stores are NONTEMPORAL (streaming) to keep L2 for mu rows.
__global__ __launch_bounds__(256) void k_aggM(
    const unsigned char* __restrict__ mu,
    unsigned char* __restrict__ s_in, unsigned char* __restrict__ s_out,
    const int* __restrict__ csr, const int* __restrict__ off,
    const int* __restrict__ deg, int nN)
{
    const int lane = threadIdx.x & 63, w = threadIdx.x >> 6;
    const int sub = lane >> 4;           // which node of the quad
    const int cl  = lane & 15;           // channel group (8 ch)
    const int g = blockIdx.x * 16 + w * 4 + sub;
    if (g >= nN) return;

    const int2 o12 = *(const int2*)&off[2 * g];
    const int2 d12 = *(const int2*)&deg[2 * g];
    const int o1 = o12.x, o2 = o12.y;
    const int d1r = (d12.x + 7) & ~7;
    const int d2r = (d12.y + 7) & ~7;
    const int m = (d1r > d2r) ? d1r : d2r;

    const unsigned loff = (unsigned)(cl * 8);

    f32x2 Ai0[4], Ai1[4], Ao0[4], Ao1[4];
    #pragma unroll
    for (int p = 0; p < 4; ++p) {
        Ai0[p] = f32x2{0.f, 0.f}; Ai1[p] = f32x2{0.f, 0.f};
        Ao0[p] = f32x2{0.f, 0.f}; Ao1[p] = f32x2{0.f, 0.f};
    }

    for (int i = 0; i < m; i += 8) {
        const int* p1 = (i < d1r) ? (csr + o1 + i) : csr;   // csr[0..8) = sentinel
        const int* p2 = (i < d2r) ? (csr + o2 + i) : csr;
        #pragma unroll
        for (int j = 0; j < 8; ++j) {
            unsigned u2 = (unsigned)__builtin_nontemporal_load(p1 + j);
            unsigned u3 = (unsigned)__builtin_nontemporal_load(p2 + j);
            uint2 q2 = *(const uint2*)(mu + (((size_t)u2 << 7) + loff));
            uint2 q3 = *(const uint2*)(mu + (((size_t)u3 << 7) + loff));
            if (j & 1) {
                Ai1[0] += fp8x2_dec<false>(q2.x);
                Ai1[1] += fp8x2_dec<true >(q2.x);
                Ai1[2] += fp8x2_dec<false>(q2.y);
                Ai1[3] += fp8x2_dec<true >(q2.y);
                Ao1[0] += fp8x2_dec<false>(q3.x);
                Ao1[1] += fp8x2_dec<true >(q3.x);
                Ao1[2] += fp8x2_dec<false>(q3.y);
                Ao1[3] += fp8x2_dec<true >(q3.y);
            } else {
                Ai0[0] += fp8x2_dec<false>(q2.x);
                Ai0[1] += fp8x2_dec<true >(q2.x);
                Ai0[2] += fp8x2_dec<false>(q2.y);
                Ai0[3] += fp8x2_dec<true >(q2.y);
                Ao0[0] += fp8x2_dec<false>(q3.x);
                Ao0[1] += fp8x2_dec<true >(q3.x);
                Ao0[2] += fp8x2_dec<false>(q3.y);
                Ao0[3] += fp8x2_dec<true >(q3.y);
            }
        }
    }

    unsigned long long wiL, woL;
    {
        f32x2 s0 = Ai0[0] + Ai1[0], s1 = Ai0[1] + Ai1[1];
        f32x2 s2 = Ai0[2] + Ai1[2], s3 = Ai0[3] + Ai1[3];
        unsigned lo = f2fp8x2(fminf(s0[0], 448.f), fminf(s0[1], 448.f)) |
                      (f2fp8x2(fminf(s1[0], 448.f), fminf(s1[1], 448.f)) << 16);
        unsigned hi = f2fp8x2(fminf(s2[0], 448.f), fminf(s2[1], 448.f)) |
                      (f2fp8x2(fminf(s3[0], 448.f), fminf(s3[1], 448.f)) << 16);
        wiL = (unsigned long long)lo | ((unsigned long long)hi << 32);
    }
    {
        f32x2 s0 = Ao0[0] + Ao1[0], s1 = Ao0[1] + Ao1[1];
        f32x2 s2 = Ao0[2] + Ao1[2], s3 = Ao0[3] + Ao1[3];
        unsigned lo = f2fp8x2(fminf(s0[0], 448.f), fminf(s0[1], 448.f)) |
                      (f2fp8x2(fminf(s1[0], 448.f), fminf(s1[1], 448.f)) << 16);
        unsigned hi = f2fp8x2(fminf(s2[0], 448.f), fminf(s2[1], 448.f)) |
                      (f2fp8x2(fminf(s3[0], 448.f), fminf(s3[1], 448.f)) << 16);
        woL = (unsigned long long)lo | ((unsigned long long)hi << 32);
    }
    __builtin_nontemporal_store(wiL,
        (unsigned long long*)&s_in [(size_t)g * C + cl * 8]);
    __builtin_nontemporal_store(woL,
        (unsigned long long*)&s_out[(size_t)g * C + cl * 8]);
}

extern "C" void kernel_launch(void* const* d_in, const int* in_sizes, int n_in,
                              void* d_out, int out_size, void* d_ws, size_t ws_size,
                              hipStream_t stream)
{
    const float* x  = (const float*)d_in[0];
    const int*   ei = (const int*)d_in[1];
    const float* W1 = (const float*)d_in[2];
    const float* W2 = (const float*)d_in[3];
    const float* W3 = (const float*)d_in[4];
    float* out = (float*)d_out;

    const int nN = in_sizes[0] / C;
    const int nE = in_sizes[1] / 2;
    const int* src = ei;
    const int* dst = ei + nE;

    const size_t SZH  = (size_t)nN * C * 2;      // bf16 node array
    const size_t SZQ  = (size_t)nN * C + C;      // fp8 node array + zero row
    char* p = (char*)d_ws;
    auto alloc = [&](size_t bytes) {
        char* r = p;
        p += (bytes + 511) & ~(size_t)511;
        return r;
    };
    unsigned short* x_emb = (unsigned short*)alloc(SZH);
    unsigned char*  mu    = (unsigned char*)alloc(SZQ);
    unsigned char*  s_in  = (unsigned char*)alloc(SZQ);
    unsigned char*  s_out = (unsigned char*)alloc(SZQ);
    unsigned short* wsw   = (unsigned short*)alloc((size_t)2 * C * C * 2);
    int* deg  = (int*)alloc((size_t)2 * nN * 4);
    int* off  = (int*)alloc((size_t)2 * nN * 4);
    int* bcnt = (int*)alloc((size_t)NBMAX * 16 * 4);
    unsigned* tmp = (unsigned*)alloc((size_t)NBMAX * BCAP * 4);
    int* csr  = (int*)alloc(((size_t)NBMAX * CCAP + 16) * 4);

    const int n2 = 2 * nN;
    const int nbuck = (n2 + 1023) >> 10;     // coarse buckets (<= NBMAX)

    const int mm_grid = (nN + 127) / 128;
    const int npart = (nE + EPB / 2 - 1) / (EPB / 2);

    // iteration 1: mu = relu(x @ W1^T); also zeroes bcnt/out/zero-row,
    // writes csr sentinel, converts W2|W3 -> wsw (bf16 swizzled)
    k_emb<<<mm_grid, 512, 0, stream>>>(x, W1, W2, W3, x_emb, mu, wsw,
                                       bcnt, out, csr, nN);

    // CSR build (fixed-capacity buckets in both tmp and csr)
    k_part2<<<npart, 512, 0, stream>>>(src, dst, bcnt, tmp, nE, nN, n2);
    k_place<<<nbuck, 512, 0, stream>>>(tmp, bcnt, off, deg, csr, n2, nN);

    // iteration 2: s = gather(mu1); mu2 = relu(x_emb + s_in@W2^T + s_out@W3^T)
    k_aggM<<<(nN + 15) / 16, 256, 0, stream>>>(mu, s_in, s_out, csr, off, deg, nN);
    k_mm3<0><<<mm_grid, 512, 0, stream>>>(s_in, s_out, wsw, x_emb, mu, out, nN);
    // iteration 3: s = gather(mu2); h_G = colsum(relu(...)) fused
    k_aggM<<<(nN + 15) / 16, 256, 0, stream>>>(mu, s_in, s_out, csr, off, deg, nN);
    k_mm3<1><<<mm_grid, 512, 0, stream>>>(s_in, s_out, wsw, x_emb, nullptr, out, nN);
}

// Round 19
// 236.211 us; speedup vs baseline: 1.1563x; 1.1563x over previous
//
#include <hip/hip_runtime.h>
#include <hip/hip_bf16.h>

#define C 128
#define NBMAX 256      // max coarse buckets (key >> 10)
#define EPB 16384      // entries per k_part2 block (8192 edges)
#define BCAP 18432     // fixed bucket capacity in tmp (mean 16.4K + 16 sigma)
#define CCAP 25600     // fixed bucket capacity in csr (BCAP + 1024*7 pad)

typedef __attribute__((ext_vector_type(8))) short bf16x8;
typedef __attribute__((ext_vector_type(4))) float f32x4;
typedef __attribute__((ext_vector_type(2))) float f32x2;

__device__ __forceinline__ unsigned short f2bf(float f) {
    unsigned u = __builtin_bit_cast(unsigned, f);
    u += 0x7fff + ((u >> 16) & 1);          // RNE
    return (unsigned short)(u >> 16);
}
__device__ __forceinline__ float bf1(unsigned short v) {
    return __builtin_bit_cast(float, (unsigned)v << 16);
}

// ---- fp8 e4m3 helpers (HW cvt on gfx950, software fallback) ----------------
__device__ __forceinline__ unsigned char f2fp8(float v) {
#if __has_builtin(__builtin_amdgcn_cvt_pk_fp8_f32)
    return (unsigned char)(__builtin_amdgcn_cvt_pk_fp8_f32(v, v, 0, false) & 0xff);
#else
    unsigned u = __builtin_bit_cast(unsigned, v);
    if (v < 0.015625f) return 0;
    u += 0x7FFFF + ((u >> 20) & 1);
    int e = (int)(u >> 23) - 120;
    int m = (u >> 20) & 7;
    if (e <= 0) return 0;
    if (e > 15) return 0x7E;
    return (unsigned char)((e << 3) | m);
#endif
}

__device__ __forceinline__ unsigned f2fp8x2(float a, float b) {
#if __has_builtin(__builtin_amdgcn_cvt_pk_fp8_f32)
    return (unsigned)(__builtin_amdgcn_cvt_pk_fp8_f32(a, b, 0, false) & 0xffff);
#else
    return (unsigned)f2fp8(a) | ((unsigned)f2fp8(b) << 8);
#endif
}

template <bool HI>
__device__ __forceinline__ f32x2 fp8x2_dec(unsigned q) {
#if __has_builtin(__builtin_amdgcn_cvt_pk_f32_fp8)
    return __builtin_amdgcn_cvt_pk_f32_fp8((int)q, HI);
#else
    unsigned short v = HI ? (unsigned short)(q >> 16) : (unsigned short)(q & 0xffff);
    auto dec1 = [](unsigned b) -> float {
        unsigned r = ((b & 0x80u) << 8) | (((b & 0x7fu) << 4) + 0x3C00u);
        if ((b & 0x78u) == 0) r = 0;
        return __builtin_bit_cast(float, r << 16);
    };
    f32x2 r; r[0] = dec1(v & 0xff); r[1] = dec1(v >> 8);
    return r;
#endif
}

// ---------------- k_emb: x_emb = x @ W1^T (bf16), mu = relu(..) (fp8) -------
// Extra duties: block 0 zeroes bcnt/out/mu-zero-row and writes csr sentinel;
// blocks 0..7 convert W2|W3 -> bf16 swizzled global (wsw) for k_mm3.
__global__ __launch_bounds__(512) void k_emb(
    const float* __restrict__ x, const float* __restrict__ W1,
    const float* __restrict__ W2, const float* __restrict__ W3,
    unsigned short* __restrict__ x_emb, unsigned char* __restrict__ mu,
    unsigned short* __restrict__ wsw, int* __restrict__ bcnt,
    float* __restrict__ out, int* __restrict__ csr, int nN)
{
    __shared__ unsigned short Wl[C * C];   // bf16, XOR-swizzled 16B chunks
    const int t = threadIdx.x;

    if (blockIdx.x == 0) {
        for (int i = t; i < NBMAX * 16; i += 512) bcnt[i] = 0;
        if (t < C) out[t] = 0.f;
        if (t < C / 4) ((unsigned*)(mu + (size_t)nN * C))[t] = 0u;
        if (t < 8) csr[t] = nN;            // global sentinel chunk -> zero row
    }
    if (blockIdx.x < 8) {   // W2|W3 -> wsw (4096 chunks of 8 elems)
        int i = blockIdx.x * 512 + t;
        int wsel = i >> 11, r = i & 2047;
        int j = r >> 4, c = r & 15;
        const float* srcp = (wsel ? W3 : W2) + j * C + c * 8;
        float4 f0 = *(const float4*)srcp;
        float4 f1 = *(const float4*)(srcp + 4);
        alignas(16) unsigned short tmp[8] = {
            f2bf(f0.x), f2bf(f0.y), f2bf(f0.z), f2bf(f0.w),
            f2bf(f1.x), f2bf(f1.y), f2bf(f1.z), f2bf(f1.w)};
        int cs = c ^ (j & 7);
        *(uint4*)&wsw[wsel * C * C + j * C + cs * 8] = *(const uint4*)tmp;
    }

    for (int i = t; i < C * C / 8; i += 512) {
        int j = i >> 4, c = i & 15;
        const float* srcp = W1 + j * C + c * 8;
        float4 f0 = *(const float4*)srcp;
        float4 f1 = *(const float4*)(srcp + 4);
        alignas(16) unsigned short tmp[8] = {
            f2bf(f0.x), f2bf(f0.y), f2bf(f0.z), f2bf(f0.w),
            f2bf(f1.x), f2bf(f1.y), f2bf(f1.z), f2bf(f1.w)};
        int cs = c ^ (j & 7);
        *(uint4*)&Wl[j * C + cs * 8] = *(const uint4*)tmp;
    }
    __syncthreads();

    const int lane = t & 63, w = t >> 6;
    const int r0 = blockIdx.x * 128 + w * 16;
    if (r0 >= nN) return;
    const int lj = lane & 15, lk = lane >> 4;
    const int arow = r0 + lj;

    bf16x8 a[4];
    #pragma unroll
    for (int ks = 0; ks < 4; ++ks) {
        const float* ap = x + (size_t)arow * C + ks * 32 + lk * 8;
        float4 f0 = *(const float4*)ap;
        float4 f1 = *(const float4*)(ap + 4);
        alignas(16) unsigned short tmp[8] = {
            f2bf(f0.x), f2bf(f0.y), f2bf(f0.z), f2bf(f0.w),
            f2bf(f1.x), f2bf(f1.y), f2bf(f1.z), f2bf(f1.w)};
        a[ks] = *(const bf16x8*)tmp;
    }

    #pragma unroll
    for (int ct = 0; ct < 8; ++ct) {
        int j = ct * 16 + lj;
        f32x4 acc = {0.f, 0.f, 0.f, 0.f};
        #pragma unroll
        for (int ks = 0; ks < 4; ++ks) {
            int slot = (ks * 4 + lk) ^ (j & 7);
            bf16x8 b = *(const bf16x8*)&Wl[j * C + slot * 8];
            acc = __builtin_amdgcn_mfma_f32_16x16x32_bf16(a[ks], b, acc, 0, 0, 0);
        }
        #pragma unroll
        for (int r = 0; r < 4; ++r) {
            int row = r0 + lk * 4 + r;
            float v = acc[r];
            x_emb[(size_t)row * C + j] = f2bf(v);
            mu[(size_t)row * C + j] = f2fp8(fminf(fmaxf(v, 0.f), 448.f));
        }
    }
}

// ---- k_mm3: mu' = relu(x_emb + s_in @ W2^T + s_out @ W3^T) -----------------
// s_in/s_out fp8; W from pre-converted wsw (bf16 swizzled).
// FINAL=0: write mu' fp8. FINAL=1: column-reduce into out[128].
template<int FINAL>
__global__ __launch_bounds__(512) void k_mm3(
    const unsigned char* __restrict__ s_in, const unsigned char* __restrict__ s_out,
    const unsigned short* __restrict__ wsw,
    const unsigned short* __restrict__ x_emb,
    unsigned char* __restrict__ mu_out, float* __restrict__ out, int nN)
{
    __shared__ unsigned short Wl[2 * C * C];   // W2 then W3, swizzled
    __shared__ float redf[8 * C];              // FINAL column partials
    const int t = threadIdx.x;
    for (int i = t; i < 2 * C * C / 8; i += 512)
        *(uint4*)&Wl[i * 8] = *(const uint4*)&wsw[i * 8];
    if (FINAL) {
        for (int i = t; i < 8 * C; i += 512) redf[i] = 0.f;
    }
    __syncthreads();

    const int lane = t & 63, w = t >> 6;
    const int r0 = blockIdx.x * 128 + w * 16;
    const int lj = lane & 15, lk = lane >> 4;
    const bool active = (r0 < nN);

    if (active) {
        const int arow = r0 + lj;
        bf16x8 a2[4], a3[4];
        #pragma unroll
        for (int ks = 0; ks < 4; ++ks) {
            uint2 qi = *(const uint2*)&s_in [(size_t)arow * C + ks * 32 + lk * 8];
            uint2 qo = *(const uint2*)&s_out[(size_t)arow * C + ks * 32 + lk * 8];
            f32x2 e0 = fp8x2_dec<false>(qi.x), e1 = fp8x2_dec<true>(qi.x);
            f32x2 e2 = fp8x2_dec<false>(qi.y), e3 = fp8x2_dec<true>(qi.y);
            a2[ks][0] = (short)f2bf(e0[0]); a2[ks][1] = (short)f2bf(e0[1]);
            a2[ks][2] = (short)f2bf(e1[0]); a2[ks][3] = (short)f2bf(e1[1]);
            a2[ks][4] = (short)f2bf(e2[0]); a2[ks][5] = (short)f2bf(e2[1]);
            a2[ks][6] = (short)f2bf(e3[0]); a2[ks][7] = (short)f2bf(e3[1]);
            f32x2 g0 = fp8x2_dec<false>(qo.x), g1 = fp8x2_dec<true>(qo.x);
            f32x2 g2 = fp8x2_dec<false>(qo.y), g3 = fp8x2_dec<true>(qo.y);
            a3[ks][0] = (short)f2bf(g0[0]); a3[ks][1] = (short)f2bf(g0[1]);
            a3[ks][2] = (short)f2bf(g1[0]); a3[ks][3] = (short)f2bf(g1[1]);
            a3[ks][4] = (short)f2bf(g2[0]); a3[ks][5] = (short)f2bf(g2[1]);
            a3[ks][6] = (short)f2bf(g3[0]); a3[ks][7] = (short)f2bf(g3[1]);
        }

        #pragma unroll
        for (int ct = 0; ct < 8; ++ct) {
            int j = ct * 16 + lj;
            f32x4 acc = {0.f, 0.f, 0.f, 0.f};
            #pragma unroll
            for (int ks = 0; ks < 4; ++ks) {
                int slot = (ks * 4 + lk) ^ (j & 7);
                bf16x8 b2 = *(const bf16x8*)&Wl[j * C + slot * 8];
                bf16x8 b3 = *(const bf16x8*)&Wl[C * C + j * C + slot * 8];
                acc = __builtin_amdgcn_mfma_f32_16x16x32_bf16(a2[ks], b2, acc, 0, 0, 0);
                acc = __builtin_amdgcn_mfma_f32_16x16x32_bf16(a3[ks], b3, acc, 0, 0, 0);
            }
            float vsum = 0.f;
            #pragma unroll
            for (int r = 0; r < 4; ++r) {
                int row = r0 + lk * 4 + r;
                float v = acc[r] + bf1(x_emb[(size_t)row * C + j]);
                v = fmaxf(v, 0.f);
                if (FINAL) vsum += v;
                else mu_out[(size_t)row * C + j] = f2fp8(fminf(v, 448.f));
            }
            if (FINAL) {
                float s = vsum;
                s += __shfl_xor(s, 16);
                s += __shfl_xor(s, 32);
                if (lk == 0) redf[w * C + j] = s;
            }
        }
    }
    if (FINAL) {
        __syncthreads();
        if (t < C) {
            float acc = 0.f;
            #pragma unroll
            for (int ww = 0; ww < 8; ++ww) acc += redf[ww * C + t];
            atomicAdd(&out[t], acc);
        }
    }
}

// ---------------- CSR build pass 1: block-local counting sort ---------------
// Fixed-capacity buckets: bucket b's span in tmp is [b*BCAP, b*BCAP + count).
__global__ __launch_bounds__(512) void k_part2(
    const int* __restrict__ src, const int* __restrict__ dst,
    int* __restrict__ bcnt, unsigned* __restrict__ tmp, int nE, int nN, int n2)
{
    __shared__ unsigned sbuf[EPB];
    __shared__ unsigned char bid[EPB];
    __shared__ int hist[NBMAX], lstart[NBMAX], cur[NBMAX], gbase[NBMAX];

    const int t = threadIdx.x;
    const int e0 = blockIdx.x * (EPB / 2);
    const int e1 = min(e0 + EPB / 2, nE);

    for (int b = t; b < NBMAX; b += 512) { hist[b] = 0; cur[b] = 0; }
    __syncthreads();

    for (int e = e0 + t; e < e1; e += 512) {
        int s = src[e], d = dst[e];
        atomicAdd(&hist[(2 * d) >> 10], 1);
        atomicAdd(&hist[(2 * s + 1) >> 10], 1);
    }
    __syncthreads();

    for (int o = 1; o < NBMAX; o <<= 1) {
        int v = 0;
        if (t < NBMAX && t >= o) v = hist[t - o];
        __syncthreads();
        if (t < NBMAX) hist[t] += v;
        __syncthreads();
    }
    if (t < NBMAX) {
        int ls = (t == 0) ? 0 : hist[t - 1];
        lstart[t] = ls;
        int c = hist[t] - ls;
        if (c > 0)
            gbase[t] = t * BCAP + atomicAdd(&bcnt[t * 16], c);
    }
    __syncthreads();

    for (int e = e0 + t; e < e1; e += 512) {
        int s = src[e], d = dst[e];
        {
            int key = 2 * d, b = key >> 10, krel = key & 1023;
            int pos = lstart[b] + atomicAdd(&cur[b], 1);
            sbuf[pos] = ((unsigned)krel << 17) | (unsigned)s;
            bid[pos] = (unsigned char)b;
        }
        {
            int key = 2 * s + 1, b = key >> 10, krel = key & 1023;
            int pos = lstart[b] + atomicAdd(&cur[b], 1);
            sbuf[pos] = ((unsigned)krel << 17) | (unsigned)d;
            bid[pos] = (unsigned char)b;
        }
    }
    __syncthreads();

    const int nent = 2 * (e1 - e0);
    for (int j = t; j < nent; j += 512) {
        int b = bid[j];
        tmp[gbase[b] + (j - lstart[b])] = sbuf[j];
    }
}

// ---------------- k_place: merged histogram + scan + off/deg + scatter ------
// Per bucket (1024 keys): fixed csr base 8 + b*CCAP, so no global scan needed.
__global__ __launch_bounds__(512) void k_place(
    const unsigned* __restrict__ tmp, const int* __restrict__ bcnt,
    int* __restrict__ off, int* __restrict__ deg, int* __restrict__ csr,
    int n2, int zrow)
{
    __shared__ int cnt[1024], excl[1024], part[512];
    const int t = threadIdx.x;
    const int b = blockIdx.x;
    const int key0 = b << 10;
    const int s0 = b * BCAP;
    const int s1 = s0 + bcnt[b * 16];
    const int pb0 = 8 + b * CCAP;

    for (int i = t; i < 1024; i += 512) cnt[i] = 0;
    __syncthreads();
    for (int i = s0 + t; i < s1; i += 512)
        atomicAdd(&cnt[tmp[i] >> 17], 1);
    __syncthreads();

    // padded exclusive scan: serial-2 + Hillis-Steele over 512 partials
    const int base = t * 2;
    int c0 = cnt[base], c1 = cnt[base + 1];
    int p0 = (c0 + 7) & ~7, p1v = (c1 + 7) & ~7;
    int s = p0 + p1v;
    part[t] = s;
    for (int o = 1; o < 512; o <<= 1) {
        __syncthreads();
        int v = (t >= o) ? part[t - o] : 0;
        __syncthreads();
        part[t] += v;
    }
    __syncthreads();
    int pe = part[t] - s;
    excl[base]     = pe;
    excl[base + 1] = pe + p0;
    __syncthreads();

    // write off/deg + pad-fill
    for (int i = t; i < 1024; i += 512) {
        int key = key0 + i;
        if (key < n2) {
            int o = pb0 + excl[i];
            off[key] = o;
            int d = cnt[i];
            deg[key] = d;
            int pd = (d + 7) & ~7;
            for (int p = d; p < pd; ++p) csr[o + p] = zrow;
        }
    }
    __syncthreads();
    for (int i = t; i < 1024; i += 512) cnt[i] = 0;   // reuse as cursors
    __syncthreads();

    for (int i = s0 + t; i < s1; i += 512) {
        unsigned p = tmp[i];
        int krel = p >> 17;
        int val  = p & 0x1FFFF;
        int pos  = pb0 + excl[krel] + atomicAdd(&cnt[krel], 1);
        csr[pos] = val;
    }
}

// ---- k_aggM: s_in[g] = sum(mu[in]), s_out[g] = sum(mu[out])  (fp8 in/out) --
// 16 lanes per node (8 ch/lane, uint2 loads), 4 nodes per wave, MLP=16.
// Padded csr; chunks past a list's end redirect to the sentinel chunk
// csr[0..8) (zero row), so the inner loop has no clamps or masks.
__global__ __launch_bounds__(256) void k_aggM(
    const unsigned char* __restrict__ mu,
    unsigned char* __restrict__ s_in, unsigned char* __restrict__ s_out,
    const int* __restrict__ csr, const int* __restrict__ off,
    const int* __restrict__ deg, int nN)
{
    const int lane = threadIdx.x & 63, w = threadIdx.x >> 6;
    const int sub = lane >> 4;           // which node of the quad
    const int cl  = lane & 15;           // channel group (8 ch)
    const int g = blockIdx.x * 16 + w * 4 + sub;
    if (g >= nN) return;

    const int2 o12 = *(const int2*)&off[2 * g];
    const int2 d12 = *(const int2*)&deg[2 * g];
    const int o1 = o12.x, o2 = o12.y;
    const int d1r = (d12.x + 7) & ~7;
    const int d2r = (d12.y + 7) & ~7;
    const int m = (d1r > d2r) ? d1r : d2r;

    const unsigned loff = (unsigned)(cl * 8);

    f32x2 Ai0[4], Ai1[4], Ao0[4], Ao1[4];
    #pragma unroll
    for (int p = 0; p < 4; ++p) {
        Ai0[p] = f32x2{0.f, 0.f}; Ai1[p] = f32x2{0.f, 0.f};
        Ao0[p] = f32x2{0.f, 0.f}; Ao1[p] = f32x2{0.f, 0.f};
    }

    for (int i = 0; i < m; i += 8) {
        const int* p1 = (i < d1r) ? (csr + o1 + i) : csr;   // csr[0..8) = sentinel
        const int* p2 = (i < d2r) ? (csr + o2 + i) : csr;
        #pragma unroll
        for (int j = 0; j < 8; ++j) {
            unsigned u2 = (unsigned)p1[j];
            unsigned u3 = (unsigned)p2[j];
            uint2 q2 = *(const uint2*)(mu + (((size_t)u2 << 7) + loff));
            uint2 q3 = *(const uint2*)(mu + (((size_t)u3 << 7) + loff));
            if (j & 1) {
                Ai1[0] += fp8x2_dec<false>(q2.x);
                Ai1[1] += fp8x2_dec<true >(q2.x);
                Ai1[2] += fp8x2_dec<false>(q2.y);
                Ai1[3] += fp8x2_dec<true >(q2.y);
                Ao1[0] += fp8x2_dec<false>(q3.x);
                Ao1[1] += fp8x2_dec<true >(q3.x);
                Ao1[2] += fp8x2_dec<false>(q3.y);
                Ao1[3] += fp8x2_dec<true >(q3.y);
            } else {
                Ai0[0] += fp8x2_dec<false>(q2.x);
                Ai0[1] += fp8x2_dec<true >(q2.x);
                Ai0[2] += fp8x2_dec<false>(q2.y);
                Ai0[3] += fp8x2_dec<true >(q2.y);
                Ao0[0] += fp8x2_dec<false>(q3.x);
                Ao0[1] += fp8x2_dec<true >(q3.x);
                Ao0[2] += fp8x2_dec<false>(q3.y);
                Ao0[3] += fp8x2_dec<true >(q3.y);
            }
        }
    }

    uint2 wi, wo;
    {
        f32x2 s0 = Ai0[0] + Ai1[0], s1 = Ai0[1] + Ai1[1];
        f32x2 s2 = Ai0[2] + Ai1[2], s3 = Ai0[3] + Ai1[3];
        wi.x = f2fp8x2(fminf(s0[0], 448.f), fminf(s0[1], 448.f)) |
               (f2fp8x2(fminf(s1[0], 448.f), fminf(s1[1], 448.f)) << 16);
        wi.y = f2fp8x2(fminf(s2[0], 448.f), fminf(s2[1], 448.f)) |
               (f2fp8x2(fminf(s3[0], 448.f), fminf(s3[1], 448.f)) << 16);
    }
    {
        f32x2 s0 = Ao0[0] + Ao1[0], s1 = Ao0[1] + Ao1[1];
        f32x2 s2 = Ao0[2] + Ao1[2], s3 = Ao0[3] + Ao1[3];
        wo.x = f2fp8x2(fminf(s0[0], 448.f), fminf(s0[1], 448.f)) |
               (f2fp8x2(fminf(s1[0], 448.f), fminf(s1[1], 448.f)) << 16);
        wo.y = f2fp8x2(fminf(s2[0], 448.f), fminf(s2[1], 448.f)) |
               (f2fp8x2(fminf(s3[0], 448.f), fminf(s3[1], 448.f)) << 16);
    }
    *(uint2*)&s_in [(size_t)g * C + cl * 8] = wi;
    *(uint2*)&s_out[(size_t)g * C + cl * 8] = wo;
}

extern "C" void kernel_launch(void* const* d_in, const int* in_sizes, int n_in,
                              void* d_out, int out_size, void* d_ws, size_t ws_size,
                              hipStream_t stream)
{
    const float* x  = (const float*)d_in[0];
    const int*   ei = (const int*)d_in[1];
    const float* W1 = (const float*)d_in[2];
    const float* W2 = (const float*)d_in[3];
    const float* W3 = (const float*)d_in[4];
    float* out = (float*)d_out;

    const int nN = in_sizes[0] / C;
    const int nE = in_sizes[1] / 2;
    const int* src = ei;
    const int* dst = ei + nE;

    const size_t SZH  = (size_t)nN * C * 2;      // bf16 node array
    const size_t SZQ  = (size_t)nN * C + C;      // fp8 node array + zero row
    char* p = (char*)d_ws;
    auto alloc = [&](size_t bytes) {
        char* r = p;
        p += (bytes + 511) & ~(size_t)511;
        return r;
    };
    unsigned short* x_emb = (unsigned short*)alloc(SZH);
    unsigned char*  mu    = (unsigned char*)alloc(SZQ);
    unsigned char*  s_in  = (unsigned char*)alloc(SZQ);
    unsigned char*  s_out = (unsigned char*)alloc(SZQ);
    unsigned short* wsw   = (unsigned short*)alloc((size_t)2 * C * C * 2);
    int* deg  = (int*)alloc((size_t)2 * nN * 4);
    int* off  = (int*)alloc((size_t)2 * nN * 4);
    int* bcnt = (int*)alloc((size_t)NBMAX * 16 * 4);
    unsigned* tmp = (unsigned*)alloc((size_t)NBMAX * BCAP * 4);
    int* csr  = (int*)alloc(((size_t)NBMAX * CCAP + 16) * 4);

    const int n2 = 2 * nN;
    const int nbuck = (n2 + 1023) >> 10;     // coarse buckets (<= NBMAX)

    const int mm_grid = (nN + 127) / 128;
    const int npart = (nE + EPB / 2 - 1) / (EPB / 2);

    // iteration 1: mu = relu(x @ W1^T); also zeroes bcnt/out/zero-row,
    // writes csr sentinel, converts W2|W3 -> wsw (bf16 swizzled)
    k_emb<<<mm_grid, 512, 0, stream>>>(x, W1, W2, W3, x_emb, mu, wsw,
                                       bcnt, out, csr, nN);

    // CSR build (fixed-capacity buckets in both tmp and csr)
    k_part2<<<npart, 512, 0, stream>>>(src, dst, bcnt, tmp, nE, nN, n2);
    k_place<<<nbuck, 512, 0, stream>>>(tmp, bcnt, off, deg, csr, n2, nN);

    // iteration 2: s = gather(mu1); mu2 = relu(x_emb + s_in@W2^T + s_out@W3^T)
    k_aggM<<<(nN + 15) / 16, 256, 0, stream>>>(mu, s_in, s_out, csr, off, deg, nN);
    k_mm3<0><<<mm_grid, 512, 0, stream>>>(s_in, s_out, wsw, x_emb, mu, out, nN);
    // iteration 3: s = gather(mu2); h_G = colsum(relu(...)) fused
    k_aggM<<<(nN + 15) / 16, 256, 0, stream>>>(mu, s_in, s_out, csr, off, deg, nN);
    k_mm3<1><<<mm_grid, 512, 0, stream>>>(s_in, s_out, wsw, x_emb, nullptr, out, nN);
}